// Round 2
// baseline (35.042 us; speedup 1.0000x reference)
//
#include <hip/hip_runtime.h>
#include <math.h>

// Problem constants (match reference)
#define VOCAB   100000
#define EMBED_D 128
#define BATCH_N 16384
#define CTX     8
#define NNEG    5

#define S1_BLOCKS 2048
#define S1_TPB    256   // 4 waves per block -> 8192 waves, 2 elements per wave
#define WPB       (S1_TPB / 64)

// Stage 1: per-block partial sums of the 6 scalar contractions.
// Each wave handles TWO batch elements: lanes 0-31 -> e0, lanes 32-63 -> e1.
// Lane owns a float4 (16 B) of the 512 B embedding row: 32 lanes x 16 B = row.
// Every gather instruction therefore moves 1 KB (two 512 B segments).
__global__ __launch_bounds__(S1_TPB, 8) void cbow_partial_kernel(
    const int* __restrict__ pos_u,   // [B, C]
    const int* __restrict__ pos_w,   // [B]
    const int* __restrict__ neg_w,   // [B, NEG]
    const float* __restrict__ W,     // [VOCAB, D]
    float* __restrict__ partials)    // [6][S1_BLOCKS]
{
    const int lane = threadIdx.x & 63;
    const int wib  = threadIdx.x >> 6;
    const int half = lane >> 5;          // which element this half-wave serves
    const int sl   = lane & 31;          // sub-lane: float4 slot within the row

    const int e = (blockIdx.x * WPB + wib) * 2 + half;   // batch element, < 16384 exactly

    const float4* __restrict__ W4 = (const float4*)W;    // 32 float4 per row
    const int4*   __restrict__ pu4 = (const int4*)pos_u; // 2 int4 per element row

    // --- index loads (broadcast within each half-wave) ---
    const int4 ua = pu4[e * 2 + 0];
    const int4 ub = pu4[e * 2 + 1];
    const int  ip = pos_w[e];
    const int  n0 = neg_w[e * NNEG + 0];
    const int  n1 = neg_w[e * NNEG + 1];
    const int  n2 = neg_w[e * NNEG + 2];
    const int  n3 = neg_w[e * NNEG + 3];
    const int  n4 = neg_w[e * NNEG + 4];

    // --- context-sum gather: us = sum_c W[pos_u[e,c]] (my float4 slice) ---
    float4 us = make_float4(0.f, 0.f, 0.f, 0.f);
    {
        const int idxs[8] = {ua.x, ua.y, ua.z, ua.w, ub.x, ub.y, ub.z, ub.w};
        #pragma unroll
        for (int c = 0; c < CTX; ++c) {
            const float4 v = W4[(size_t)idxs[c] * (EMBED_D / 4) + sl];
            us.x += v.x; us.y += v.y; us.z += v.z; us.w += v.w;
        }
    }

    // --- 6 target-row gathers + dot partials ---
    const float4 wp = W4[(size_t)ip * (EMBED_D / 4) + sl];
    const float4 w0 = W4[(size_t)n0 * (EMBED_D / 4) + sl];
    const float4 w1 = W4[(size_t)n1 * (EMBED_D / 4) + sl];
    const float4 w2 = W4[(size_t)n2 * (EMBED_D / 4) + sl];
    const float4 w3 = W4[(size_t)n3 * (EMBED_D / 4) + sl];
    const float4 w4 = W4[(size_t)n4 * (EMBED_D / 4) + sl];

    float vals[6];
    vals[0] = us.x * wp.x + us.y * wp.y + us.z * wp.z + us.w * wp.w;
    vals[1] = us.x * w0.x + us.y * w0.y + us.z * w0.z + us.w * w0.w;
    vals[2] = us.x * w1.x + us.y * w1.y + us.z * w1.z + us.w * w1.w;
    vals[3] = us.x * w2.x + us.y * w2.y + us.z * w2.z + us.w * w2.w;
    vals[4] = us.x * w3.x + us.y * w3.y + us.z * w3.z + us.w * w3.w;
    vals[5] = us.x * w4.x + us.y * w4.y + us.z * w4.z + us.w * w4.w;

    // --- full-wave reduction (both halves sum into the same scalars) ---
    #pragma unroll
    for (int k = 0; k < 6; ++k) {
        float v = vals[k];
        #pragma unroll
        for (int off = 32; off > 0; off >>= 1)
            v += __shfl_down(v, off, 64);
        vals[k] = v;
    }

    __shared__ float sred[WPB][6];
    if (lane == 0) {
        #pragma unroll
        for (int k = 0; k < 6; ++k) sred[wib][k] = vals[k];
    }
    __syncthreads();

    if (threadIdx.x < 6) {
        float s = 0.f;
        #pragma unroll
        for (int w = 0; w < WPB; ++w) s += sred[w][threadIdx.x];
        partials[threadIdx.x * S1_BLOCKS + blockIdx.x] = s;   // [k][block] layout
    }
}

// Stage 2: 6 waves, wave k reduces partials[k][*] coalesced; thread 0 epilogue.
__global__ __launch_bounds__(384) void cbow_final_kernel(
    const float* __restrict__ partials, float* __restrict__ out)
{
    const int wave = threadIdx.x >> 6;   // 0..5 -> k
    const int lane = threadIdx.x & 63;

    float s = 0.f;
    for (int i = lane; i < S1_BLOCKS; i += 64)
        s += partials[wave * S1_BLOCKS + i];
    #pragma unroll
    for (int off = 32; off > 0; off >>= 1)
        s += __shfl_down(s, off, 64);

    __shared__ float sv[6];
    if (lane == 0) sv[wave] = s;
    __syncthreads();

    if (threadIdx.x == 0) {
        // log_sigmoid(x) = min(x,0) - log1p(exp(-|x|))
        const float spos = sv[0];
        float loss = -(fminf(spos, 0.f) - log1pf(expf(-fabsf(spos))));
        #pragma unroll
        for (int k = 1; k < 6; ++k) {
            const float x = -sv[k];      // log_sigmoid(-s_neg)
            loss -= (fminf(x, 0.f) - log1pf(expf(-fabsf(x))));
        }
        out[0] = loss;
    }
}

extern "C" void kernel_launch(void* const* d_in, const int* in_sizes, int n_in,
                              void* d_out, int out_size, void* d_ws, size_t ws_size,
                              hipStream_t stream) {
    const int*   pos_u = (const int*)d_in[0];
    const int*   pos_w = (const int*)d_in[1];
    const int*   neg_w = (const int*)d_in[2];
    const float* W     = (const float*)d_in[3];
    float* out = (float*)d_out;
    float* partials = (float*)d_ws;   // 6*S1_BLOCKS floats = 48 KB

    cbow_partial_kernel<<<S1_BLOCKS, S1_TPB, 0, stream>>>(pos_u, pos_w, neg_w, W, partials);
    cbow_final_kernel<<<1, 384, 0, stream>>>(partials, out);
}

// Round 3
// 29.577 us; speedup vs baseline: 1.1848x; 1.1848x over previous
//
#include <hip/hip_runtime.h>
#include <math.h>

// Problem constants (match reference)
#define VOCAB   100000
#define EMBED_D 128
#define BATCH_N 16384
#define CTX     8
#define NNEG    5

#define NBLOCKS 1024
#define TPB     256                     // 4 waves/block
#define WPB     (TPB / 64)
#define NWAVES  (NBLOCKS * WPB)         // 4096 waves
#define EPW     (BATCH_N / NWAVES)      // 4 elements per wave (blocked)

// Stage 1: per-block partials of the 6 scalar contractions.
// Wave g owns elements [g*4, g*4+4), processed as two interleaved pairs so
// ~28 gathers are in flight at once. Lane i owns dims [2i, 2i+1] (float2);
// a wave gather = one contiguous 512 B row segment. All index loads are
// wave-uniform (readfirstlane base) -> scalar s_load_dwordx*.
__global__ __launch_bounds__(TPB) void cbow_partial_kernel(
    const int* __restrict__ pos_u,   // [B, C]
    const int* __restrict__ pos_w,   // [B]
    const int* __restrict__ neg_w,   // [B, NEG]
    const float* __restrict__ W,     // [VOCAB, D]
    float* __restrict__ partials)    // [6][NBLOCKS]
{
    const int lane = threadIdx.x & 63;
    const int wib  = threadIdx.x >> 6;
    const int g    = blockIdx.x * WPB + wib;

    const float2* __restrict__ W2 = (const float2*)W;   // 64 float2 per row

    float accs[6] = {0.f, 0.f, 0.f, 0.f, 0.f, 0.f};

    const int base = __builtin_amdgcn_readfirstlane(g * EPW);

    #pragma unroll
    for (int p = 0; p < EPW / 2; ++p) {
        const int e0 = base + 2 * p;
        const int e1 = e0 + 1;

        // ---- wave-uniform index loads (contiguous -> wide s_loads) ----
        int c0[CTX], c1[CTX];
        #pragma unroll
        for (int c = 0; c < CTX; ++c) {
            c0[c] = pos_u[e0 * CTX + c];
            c1[c] = pos_u[e1 * CTX + c];
        }
        const int ip0 = pos_w[e0];
        const int ip1 = pos_w[e1];
        int n0[NNEG], n1[NNEG];
        #pragma unroll
        for (int n = 0; n < NNEG; ++n) {
            n0[n] = neg_w[e0 * NNEG + n];
            n1[n] = neg_w[e1 * NNEG + n];
        }

        // ---- context-sum gathers for both elements (16 independent loads) ----
        float2 us0 = make_float2(0.f, 0.f);
        float2 us1 = make_float2(0.f, 0.f);
        #pragma unroll
        for (int c = 0; c < CTX; ++c) {
            const float2 a = W2[(size_t)c0[c] * (EMBED_D / 2) + lane];
            const float2 b = W2[(size_t)c1[c] * (EMBED_D / 2) + lane];
            us0.x += a.x; us0.y += a.y;
            us1.x += b.x; us1.y += b.y;
        }

        // ---- 12 target-row gathers + dot partials ----
        {
            const float2 a = W2[(size_t)ip0 * (EMBED_D / 2) + lane];
            const float2 b = W2[(size_t)ip1 * (EMBED_D / 2) + lane];
            accs[0] += us0.x * a.x + us0.y * a.y
                     + us1.x * b.x + us1.y * b.y;
        }
        #pragma unroll
        for (int n = 0; n < NNEG; ++n) {
            const float2 a = W2[(size_t)n0[n] * (EMBED_D / 2) + lane];
            const float2 b = W2[(size_t)n1[n] * (EMBED_D / 2) + lane];
            accs[1 + n] += us0.x * a.x + us0.y * a.y
                         + us1.x * b.x + us1.y * b.y;
        }
    }

    // ---- wave reduction of the 6 accumulators ----
    #pragma unroll
    for (int k = 0; k < 6; ++k) {
        float v = accs[k];
        #pragma unroll
        for (int off = 32; off > 0; off >>= 1)
            v += __shfl_down(v, off, 64);
        accs[k] = v;
    }

    __shared__ float sred[WPB][6];
    if (lane == 0) {
        #pragma unroll
        for (int k = 0; k < 6; ++k) sred[wib][k] = accs[k];
    }
    __syncthreads();

    if (threadIdx.x < 6) {
        float s = 0.f;
        #pragma unroll
        for (int w = 0; w < WPB; ++w) s += sred[w][threadIdx.x];
        partials[threadIdx.x * NBLOCKS + blockIdx.x] = s;   // [k][block]
    }
}

// Stage 2: 6 waves; wave k reduces partials[k][*] coalesced; thread 0 epilogue.
__global__ __launch_bounds__(384) void cbow_final_kernel(
    const float* __restrict__ partials, float* __restrict__ out)
{
    const int wave = threadIdx.x >> 6;   // 0..5 -> k
    const int lane = threadIdx.x & 63;

    float s = 0.f;
    for (int i = lane; i < NBLOCKS; i += 64)
        s += partials[wave * NBLOCKS + i];
    #pragma unroll
    for (int off = 32; off > 0; off >>= 1)
        s += __shfl_down(s, off, 64);

    __shared__ float sv[6];
    if (lane == 0) sv[wave] = s;
    __syncthreads();

    if (threadIdx.x == 0) {
        // log_sigmoid(x) = min(x,0) - log1p(exp(-|x|))
        const float spos = sv[0];
        float loss = -(fminf(spos, 0.f) - log1pf(expf(-fabsf(spos))));
        #pragma unroll
        for (int k = 1; k < 6; ++k) {
            const float x = -sv[k];      // log_sigmoid(-s_neg)
            loss -= (fminf(x, 0.f) - log1pf(expf(-fabsf(x))));
        }
        out[0] = loss;
    }
}

extern "C" void kernel_launch(void* const* d_in, const int* in_sizes, int n_in,
                              void* d_out, int out_size, void* d_ws, size_t ws_size,
                              hipStream_t stream) {
    const int*   pos_u = (const int*)d_in[0];
    const int*   pos_w = (const int*)d_in[1];
    const int*   neg_w = (const int*)d_in[2];
    const float* W     = (const float*)d_in[3];
    float* out = (float*)d_out;
    float* partials = (float*)d_ws;   // 6*NBLOCKS floats = 24 KB

    cbow_partial_kernel<<<NBLOCKS, TPB, 0, stream>>>(pos_u, pos_w, neg_w, W, partials);
    cbow_final_kernel<<<1, 384, 0, stream>>>(partials, out);
}